// Round 11
// baseline (164.500 us; speedup 1.0000x reference)
//
#include <hip/hip_runtime.h>
#include <hip/hip_bf16.h>
#include <math.h>

#define B_TOT 4096
#define T_LEN 200
#define E_DIM 12
#define LOG2E 1.44269504088896340736f

typedef __attribute__((ext_vector_type(8))) short bf16x8;
typedef __attribute__((ext_vector_type(4))) float f32x4;
typedef unsigned short ushort_t;

__device__ inline unsigned short f2bf(float f) {
    union { float f; unsigned u; } x; x.f = f;
    unsigned r = x.u + 0x7FFFu + ((x.u >> 16) & 1u);
    return (unsigned short)(r >> 16);
}
__device__ inline unsigned pk_bf16(float a, float b) {
    float2 t; t.x = a; t.y = b;
    __hip_bfloat162 h = __float22bfloat162_rn(t);
    union { __hip_bfloat162 h; unsigned u; } cv; cv.h = h;
    return cv.u;
}

#define A0_STR 40   // ushorts/row (32 data + 8 pad) = 80 B: 16B-aligned, banks spread
#define H_STR  104  // ushorts/row (96 data + 8 pad) = 208 B
#define W1_STR 104  // layer-1 LDS weight rows
#define W0_STR 40   // layer-0 LDS weight rows

// SINGLE kernel: weight prep fused in (each block builds its LDS tables from
// the raw inputs; ~30 KB of weights broadcast-cached in L2/L3 across blocks).
// One batch per wave; per-wave-private A0/H/Aseg; one startup barrier.
// LDS tables:
//   w0e2L ushort[80][W0_STR]: k0..11=Wk_eff=W0[12+k]-W0[24+k], k12..23=Wqk=W0[36+..], else 0
//   w1eL  ushort[48][W1_STR]: n<40: k<80->W1[k][n], k80->b1[n]; n==40: k80->1 (abias ch); else 0
//   d0cL  float4[80] = {-rs, mm0*rs, a0, 1-a0}, rs=rsqrt(mv0+eps)*log2e
//   d1cL  float4[48] = {-rs1, mm1*rs1, a1*ak, (1-a1)*ak}; j==40: {0,0,abias,0}
__global__ __launch_bounds__(256, 3) void din_fused(
    const float* __restrict__ query, const float* __restrict__ keys,
    const float* __restrict__ W0, const float* __restrict__ b0v,
    const float* __restrict__ W1, const float* __restrict__ b1v,
    const float* __restrict__ a0v, const float* __restrict__ a1v,
    const float* __restrict__ mm0, const float* __restrict__ mv0,
    const float* __restrict__ mm1, const float* __restrict__ mv1,
    const float* __restrict__ akp, const float* __restrict__ abp,
    float* __restrict__ out)
{
    // Aseg FIRST: phase-2 A-frag garbage rows (l15>0) overflow into A0, in-bounds.
    __shared__ __align__(16) ushort_t Aseg[4 * 64];             //   512 B
    __shared__ __align__(16) ushort_t A0[4 * 64 * A0_STR];      // 20480 B
    __shared__ __align__(16) ushort_t H[4 * 16 * H_STR];        // 13312 B
    __shared__ __align__(16) f32x4 d0cL[80];                    //  1280 B
    __shared__ __align__(16) f32x4 d1cL[48];                    //   768 B
    __shared__ __align__(16) ushort_t w1eL[48 * W1_STR];        //  9984 B
    __shared__ __align__(16) ushort_t w0e2L[80 * W0_STR];       //  6400 B

    const int tid = threadIdx.x;
    const int lane = tid & 63;
    const int w = tid >> 6;
    const int l15 = lane & 15;
    const int quad = lane >> 4;
    const int b = blockIdx.x * 4 + w;

    ushort_t* A0w = &A0[w * 64 * A0_STR];
    ushort_t* Hw  = &H[w * 16 * H_STR];
    ushort_t* Asw = &Aseg[w * 64];

    // ======== fused prep: build weight tables in LDS ========
    for (int idx = tid; idx < 80 * 32; idx += 256) {
        int n = idx >> 5, k = idx & 31;
        float v = 0.0f;
        if (k < 12)       v = W0[(12 + k) * 80 + n] - W0[(24 + k) * 80 + n];
        else if (k < 24)  v = W0[(36 + (k - 12)) * 80 + n];
        w0e2L[n * W0_STR + k] = f2bf(v);
    }
    for (int idx = tid; idx < 48 * 96; idx += 256) {
        int n = idx / 96, k = idx - n * 96;
        float v = 0.0f;
        if (n < 40) {
            if (k < 80)       v = W1[k * 40 + n];
            else if (k == 80) v = b1v[n];
        } else if (n == 40 && k == 80) {
            v = 1.0f;                     // abias channel: z = 1
        }
        w1eL[n * W1_STR + k] = f2bf(v);
    }
    for (int o = tid; o < 80; o += 256) {
        float rs = rsqrtf(mv0[o] + 1e-9f) * LOG2E;
        f32x4 dv; dv.x = -rs; dv.y = mm0[o] * rs; dv.z = a0v[o]; dv.w = 1.0f - a0v[o];
        d0cL[o] = dv;
    }
    if (tid < 48) {
        int j = tid;
        f32x4 dv; dv.x = 0.f; dv.y = 0.f; dv.z = 0.f; dv.w = 0.f;
        if (j < 40) {
            float rs = rsqrtf(mv1[j] + 1e-9f) * LOG2E;
            dv.x = -rs; dv.y = mm1[j] * rs;
            dv.z = a1v[j] * akp[j]; dv.w = (1.0f - a1v[j]) * akp[j];
        } else if (j == 40) {
            dv.z = abp[0];   // z=1 -> tt=0 -> pg=.5, fma(.5, w=0, z=ab) = ab
        }
        d1cL[j] = dv;
    }

    // ---- per-batch query ----
    float qq[12];
    {
        const float4* qp = (const float4*)(query + (size_t)b * E_DIM);
        float4 q0 = qp[0], q1 = qp[1], q2 = qp[2];
        qq[0]=q0.x; qq[1]=q0.y; qq[2]=q0.z; qq[3]=q0.w;
        qq[4]=q1.x; qq[5]=q1.y; qq[6]=q1.z; qq[7]=q1.w;
        qq[8]=q2.x; qq[9]=q2.y; qq[10]=q2.z; qq[11]=q2.w;
    }

    // ---- z0q[5] = b0[n] + q·Wq_eff[.][n], n = nt*16+l15 (direct f32, L2-hot) ----
    float z0q[5];
    #pragma unroll
    for (int nt = 0; nt < 5; ++nt) {
        int n = nt * 16 + l15;
        float z = b0v[n];
        #pragma unroll
        for (int i = 0; i < 12; ++i)
            z = fmaf(qq[i], W0[i * 80 + n] + W0[(24 + i) * 80 + n], z);
        z0q[nt] = z;
    }

    // ---- one-time LDS inits (wave-private) ----
    if (quad == 0) {   // H constant tail: k=80 -> 1.0, k=81..95 -> 0
        bf16x8 one8 = {(short)0x3F80, 0, 0, 0, 0, 0, 0, 0};
        bf16x8 zero8 = {0, 0, 0, 0, 0, 0, 0, 0};
        *(bf16x8*)(Hw + l15 * H_STR + 80) = one8;
        *(bf16x8*)(Hw + l15 * H_STR + 88) = zero8;
    }
    {   // A0 row zero-pad (elements 24..31) never changes across chunks
        uint4 z4; z4.x = 0u; z4.y = 0u; z4.z = 0u; z4.w = 0u;
        ((uint4*)(A0w + lane * A0_STR))[3] = z4;
    }

    __syncthreads();   // all LDS tables visible (one-time; not in hot loop)

    f32x4 acc2 = {0.f, 0.f, 0.f, 0.f};   // phase-2: C[0][e] = sum_t sc_t * k_t[e]

    for (int c = 0; c < 4; ++c) {
        const int t0 = c * 64;
        const int myT = t0 + lane;
        const bool valid = myT < T_LEN;

        // ---- stage A0 row [k bf16(12) | qk bf16(12) | 0-pad(8, static)] ----
        float kk[12];
        if (valid) {
            const float4* kp = (const float4*)(keys + ((size_t)b * T_LEN + myT) * E_DIM);
            float4 k0 = kp[0], k1 = kp[1], k2 = kp[2];
            kk[0]=k0.x; kk[1]=k0.y; kk[2]=k0.z; kk[3]=k0.w;
            kk[4]=k1.x; kk[5]=k1.y; kk[6]=k1.z; kk[7]=k1.w;
            kk[8]=k2.x; kk[9]=k2.y; kk[10]=k2.z; kk[11]=k2.w;
        } else {
            #pragma unroll
            for (int i = 0; i < 12; ++i) kk[i] = 0.0f;
        }
        {
            unsigned kw[6], qkw[6];
            #pragma unroll
            for (int i = 0; i < 6; ++i)
                kw[i] = pk_bf16(kk[2 * i], kk[2 * i + 1]);
            #pragma unroll
            for (int i = 0; i < 6; ++i)
                qkw[i] = pk_bf16(qq[2 * i] * kk[2 * i], qq[2 * i + 1] * kk[2 * i + 1]);
            uint4* dst = (uint4*)(A0w + lane * A0_STR);
            uint4 v0, v1, v2;
            v0.x = kw[0];  v0.y = kw[1];  v0.z = kw[2];  v0.w = kw[3];
            v1.x = kw[4];  v1.y = kw[5];  v1.z = qkw[0]; v1.w = qkw[1];
            v2.x = qkw[2]; v2.y = qkw[3]; v2.z = qkw[4]; v2.w = qkw[5];
            dst[0] = v0; dst[1] = v1; dst[2] = v2;
        }
        // No Asw clear needed — stale scores only multiply zeroed key columns.

        const int ntiles = (c < 3) ? 4 : 1;
        for (int ti = 0; ti < ntiles; ++ti) {
            bf16x8 a0 = *(const bf16x8*)(A0w + (ti * 16 + l15) * A0_STR + quad * 8);

            // layer 0 + dice0, fused per nt (one acc live at a time)
            #pragma unroll
            for (int nt = 0; nt < 5; ++nt) {
                bf16x8 b0 = *(const bf16x8*)(w0e2L + (nt * 16 + l15) * W0_STR + quad * 8);
                float zq = z0q[nt];
                f32x4 cc = {zq, zq, zq, zq};          // bias folded into C-init
                cc = __builtin_amdgcn_mfma_f32_16x16x32_bf16(a0, b0, cc, 0, 0, 0);
                f32x4 dc = d0cL[nt * 16 + l15];
                float h[4];
                #pragma unroll
                for (int r = 0; r < 4; ++r) {
                    float z = cc[r];
                    float pg = __builtin_amdgcn_rcpf(
                        1.0f + __builtin_amdgcn_exp2f(fmaf(z, dc.x, dc.y)));
                    h[r] = z * fmaf(pg, dc.w, dc.z);
                }
                unsigned u01 = pk_bf16(h[0], h[1]);
                unsigned u23 = pk_bf16(h[2], h[3]);
                ushort_t* hcol = Hw + (quad * 4) * H_STR + nt * 16 + l15;
                hcol[0 * H_STR] = (ushort_t)u01;
                hcol[1 * H_STR] = (ushort_t)(u01 >> 16);
                hcol[2 * H_STR] = (ushort_t)u23;
                hcol[3 * H_STR] = (ushort_t)(u23 >> 16);
            }

            // layer 1: [16x96]·[96x48], 9 MFMA; B-frags from LDS
            bf16x8 af[3];
            #pragma unroll
            for (int ks = 0; ks < 3; ++ks)
                af[ks] = *(const bf16x8*)(Hw + l15 * H_STR + ks * 32 + quad * 8);
            float s[4] = {0.f, 0.f, 0.f, 0.f};
            #pragma unroll
            for (int nt = 0; nt < 3; ++nt) {
                f32x4 cc = {0.f, 0.f, 0.f, 0.f};
                #pragma unroll
                for (int ks = 0; ks < 3; ++ks) {
                    bf16x8 bf = *(const bf16x8*)(w1eL + (nt * 16 + l15) * W1_STR
                                                 + ks * 32 + quad * 8);
                    cc = __builtin_amdgcn_mfma_f32_16x16x32_bf16(af[ks], bf, cc, 0, 0, 0);
                }
                f32x4 dc1 = d1cL[nt * 16 + l15];
                #pragma unroll
                for (int r = 0; r < 4; ++r) {
                    float z = cc[r];
                    float pg = __builtin_amdgcn_rcpf(
                        1.0f + __builtin_amdgcn_exp2f(fmaf(z, dc1.x, dc1.y)));
                    s[r] = fmaf(z, fmaf(pg, dc1.w, dc1.z), s[r]);
                }
            }
            // reduce over 16 j-lanes (abias arrives via the j=40 channel)
            #pragma unroll
            for (int m = 1; m < 16; m <<= 1) {
                #pragma unroll
                for (int r = 0; r < 4; ++r) s[r] += __shfl_xor(s[r], m, 64);
            }
            if (l15 == 0) {
                const int tb = t0 + ti * 16 + quad * 4;
                float v0 = (tb + 0 < T_LEN) ? s[0] : 0.0f;
                float v1 = (tb + 1 < T_LEN) ? s[1] : 0.0f;
                float v2 = (tb + 2 < T_LEN) ? s[2] : 0.0f;
                float v3 = (tb + 3 < T_LEN) ? s[3] : 0.0f;
                unsigned lo = pk_bf16(v0, v1), hi = pk_bf16(v2, v3);
                unsigned long long pk = (unsigned long long)lo
                                      | ((unsigned long long)hi << 32);
                *(unsigned long long*)(Asw + ti * 16 + quad * 4) = pk;
            }
        }

        // ---- phase 2 partial: 2 MFMA, K=64 (skip all-zero upper half at c=3) ----
        const int nks = (c < 3) ? 2 : 1;
        for (int ks = 0; ks < nks; ++ks) {
            bf16x8 pa = *(const bf16x8*)(Asw + l15 * 64 + ks * 32 + quad * 8);
            bf16x8 bk;
            #pragma unroll
            for (int j = 0; j < 8; ++j)
                bk[j] = (short)A0w[(ks * 32 + quad * 8 + j) * A0_STR + l15];
            acc2 = __builtin_amdgcn_mfma_f32_16x16x32_bf16(pa, bk, acc2, 0, 0, 0);
        }
    }

    if (quad == 0 && l15 < 12)
        out[(size_t)b * E_DIM + l15] = acc2[0];
}

extern "C" void kernel_launch(void* const* d_in, const int* in_sizes, int n_in,
                              void* d_out, int out_size, void* d_ws, size_t ws_size,
                              hipStream_t stream) {
    const float* query = (const float*)d_in[0];
    const float* keys  = (const float*)d_in[1];
    // d_in[2] = mask (unused: reference bug matmuls unmasked scores)
    const float* W0  = (const float*)d_in[3];
    const float* b0v = (const float*)d_in[4];
    const float* W1  = (const float*)d_in[5];
    const float* b1v = (const float*)d_in[6];
    const float* a0  = (const float*)d_in[7];
    const float* a1  = (const float*)d_in[8];
    const float* mm0 = (const float*)d_in[9];
    const float* mv0 = (const float*)d_in[10];
    const float* mm1 = (const float*)d_in[11];
    const float* mv1 = (const float*)d_in[12];
    const float* ak  = (const float*)d_in[13];
    const float* ab  = (const float*)d_in[14];
    float* out = (float*)d_out;

    hipLaunchKernelGGL(din_fused, dim3(B_TOT / 4), dim3(256), 0, stream,
                       query, keys, W0, b0v, W1, b1v, a0, a1,
                       mm0, mv0, mm1, mv1, ak, ab, out);
}

// Round 12
// 152.459 us; speedup vs baseline: 1.0790x; 1.0790x over previous
//
#include <hip/hip_runtime.h>
#include <hip/hip_bf16.h>
#include <math.h>

#define B_TOT 4096
#define T_LEN 200
#define E_DIM 12
#define LOG2E 1.44269504088896340736f

typedef __attribute__((ext_vector_type(8))) short bf16x8;
typedef __attribute__((ext_vector_type(4))) float f32x4;
typedef unsigned short ushort_t;

// ---- ws byte layout ----
//  [0     ..  5119]  w0e2 ushort[80][32]: k0..11=Wk_eff, k12..23=Wqk, else 0
//  [5120  .. 10239]  wq   ushort[80][32]: k0..11=Wq_eff, k12=b0, else 0
//  [10240 .. 19455]  w1e  ushort[48][96]: n<40: k<80->W1[k][n], k80->b1[n];
//                         n==40: k80->1.0 (abias channel); else 0
//  [19456 .. 20735]  d0c  float4[80] = {-rs, mm0*rs, a0, 1-a0},  rs=rsqrt(mv0+eps)*log2e
//  [20736 .. 21503]  d1c  float4[48] = {-rs1, mm1*rs1, a1*ak, (1-a1)*ak};
//                         j==40: {0,0,abias,0} -> contributes exactly abias; 0 for j>40

__device__ inline unsigned short f2bf(float f) {
    union { float f; unsigned u; } x; x.f = f;
    unsigned r = x.u + 0x7FFFu + ((x.u >> 16) & 1u);
    return (unsigned short)(r >> 16);
}
__device__ inline unsigned pk_bf16(float a, float b) {
    float2 t; t.x = a; t.y = b;
    __hip_bfloat162 h = __float22bfloat162_rn(t);
    union { __hip_bfloat162 h; unsigned u; } cv; cv.h = h;
    return cv.u;
}

__global__ __launch_bounds__(256) void din_prep(
    const float* __restrict__ W0, const float* __restrict__ b0v,
    const float* __restrict__ W1, const float* __restrict__ b1v,
    const float* __restrict__ a0, const float* __restrict__ a1,
    const float* __restrict__ mm0, const float* __restrict__ mv0,
    const float* __restrict__ mm1, const float* __restrict__ mv1,
    const float* __restrict__ ak, const float* __restrict__ ab,
    void* __restrict__ wsv)
{
    unsigned char* wsb = (unsigned char*)wsv;
    ushort_t* w0e2 = (ushort_t*)wsb;
    ushort_t* wq   = (ushort_t*)(wsb + 5120);
    ushort_t* w1e  = (ushort_t*)(wsb + 10240);
    float* d0c = (float*)(wsb + 19456);
    float* d1c = (float*)(wsb + 20736);

    int idx = blockIdx.x * 256 + threadIdx.x;   // 0..10239
    if (idx < 2560) {
        int n = idx >> 5, k = idx & 31;
        float v = 0.0f;
        if (k < 12)       v = W0[(12 + k) * 80 + n] - W0[(24 + k) * 80 + n];
        else if (k < 24)  v = W0[(36 + (k - 12)) * 80 + n];
        w0e2[n * 32 + k] = f2bf(v);
    } else if (idx < 5120) {
        int v2 = idx - 2560;
        int n = v2 >> 5, k = v2 & 31;
        float v = 0.0f;
        if (k < 12)       v = W0[k * 80 + n] + W0[(24 + k) * 80 + n];
        else if (k == 12) v = b0v[n];
        wq[n * 32 + k] = f2bf(v);
    } else if (idx < 9728) {
        int v2 = idx - 5120;
        int n = v2 / 96, k = v2 - n * 96;
        float v = 0.0f;
        if (n < 40) {
            if (k < 80)       v = W1[k * 40 + n];
            else if (k == 80) v = b1v[n];
        } else if (n == 40 && k == 80) {
            v = 1.0f;                     // abias channel: z = 1
        }
        w1e[n * 96 + k] = f2bf(v);
    } else if (idx < 10048) {
        int v2 = idx - 9728;
        int o = v2 >> 2, c = v2 & 3;
        float rs = rsqrtf(mv0[o] + 1e-9f) * LOG2E;
        float val = (c == 0) ? -rs : (c == 1) ? mm0[o] * rs : (c == 2) ? a0[o] : 1.0f - a0[o];
        d0c[o * 4 + c] = val;
    } else {
        int v2 = idx - 10048;
        int j = v2 >> 2, c = v2 & 3;
        float val = 0.0f;
        if (j < 40) {
            float rs = rsqrtf(mv1[j] + 1e-9f) * LOG2E;
            val = (c == 0) ? -rs : (c == 1) ? mm1[j] * rs : (c == 2) ? a1[j] * ak[j]
                                                          : (1.0f - a1[j]) * ak[j];
        } else if (j == 40 && c == 2) {
            val = ab[0];   // z=1 -> pg=.5, fma(.5, w=0, z=ab) = ab
        }
        d1c[j * 4 + c] = val;
    }
}

#define A0_STR 40   // ushorts/row (32 data + 8 pad) = 80 B
#define H_STR  104  // ushorts/row (96 data + 8 pad) = 208 B

// One batch per wave; zero in-loop barriers. (256,2): 256 unified regs — the
// 2-waves/SIMD wall is accepted (R5-R10: can't cross it without spilling).
// The lever here is LATENCY: double-buffered H (2 slots/wave) + 2-tile
// software pipeline breaks the per-tile LDS WAR serialization
// (tile i+1 H-writes no longer wait on tile i H-reads).
__global__ __launch_bounds__(256, 2) void din_mfma(
    const float* __restrict__ query, const float* __restrict__ keys,
    const void* __restrict__ wsv, float* __restrict__ out)
{
    // Aseg FIRST: phase-2 A-frag garbage rows (l15>0) overflow into A0, in-bounds.
    __shared__ __align__(16) ushort_t Aseg[4 * 64];                 //   512 B
    __shared__ __align__(16) ushort_t A0[4 * 64 * A0_STR];          // 20480 B
    __shared__ __align__(16) ushort_t H[4 * 2 * 16 * H_STR];        // 26624 B (2 slots/wave)
    __shared__ __align__(16) f32x4 d0cL[80];                        //  1280 B
    __shared__ __align__(16) f32x4 d1cL[48];                        //   768 B
                                                                    // 49664 B -> 2 blk/CU
    const unsigned char* wsb = (const unsigned char*)wsv;
    const ushort_t* w0e2 = (const ushort_t*)wsb;
    const ushort_t* wq   = (const ushort_t*)(wsb + 5120);
    const ushort_t* w1e  = (const ushort_t*)(wsb + 10240);
    const f32x4* d0cp = (const f32x4*)(wsb + 19456);
    const f32x4* d1cp = (const f32x4*)(wsb + 20736);

    const int tid = threadIdx.x;
    const int lane = tid & 63;
    const int w = tid >> 6;
    const int l15 = lane & 15;
    const int quad = lane >> 4;
    const int b = blockIdx.x * 4 + w;

    ushort_t* A0w = &A0[w * 64 * A0_STR];
    ushort_t* HwA = &H[(w * 2 + 0) * 16 * H_STR];
    ushort_t* HwB = &H[(w * 2 + 1) * 16 * H_STR];
    ushort_t* Asw = &Aseg[w * 64];

    // ---- stage dice consts into LDS (one-time) ----
    if (tid < 80)        d0cL[tid] = d0cp[tid];
    else if (tid < 128)  d1cL[tid - 80] = d1cp[tid - 80];

    // ---- register-resident weights (loop-invariant; 56 VGPRs, budget 256) ----
    bf16x8 b0f[5];
    #pragma unroll
    for (int nt = 0; nt < 5; ++nt)
        b0f[nt] = *(const bf16x8*)(w0e2 + (nt * 16 + l15) * 32 + quad * 8);
    bf16x8 b1f[3][3];
    #pragma unroll
    for (int nt = 0; nt < 3; ++nt)
        #pragma unroll
        for (int ks = 0; ks < 3; ++ks)
            b1f[nt][ks] = *(const bf16x8*)(w1e + (nt * 16 + l15) * 96 + ks * 32 + quad * 8);

    // ---- per-batch query ----
    float qq[12];
    {
        const float4* qp = (const float4*)(query + (size_t)b * E_DIM);
        float4 q0 = qp[0], q1 = qp[1], q2 = qp[2];
        qq[0]=q0.x; qq[1]=q0.y; qq[2]=q0.z; qq[3]=q0.w;
        qq[4]=q1.x; qq[5]=q1.y; qq[6]=q1.z; qq[7]=q1.w;
        qq[8]=q2.x; qq[9]=q2.y; qq[10]=q2.z; qq[11]=q2.w;
    }

    // ---- z0q[5]: per-batch bias row via 5 one-off MFMAs (broadcast A-row) ----
    float z0q[5];
    {
        unsigned p01 = pk_bf16(qq[0], qq[1]), p23 = pk_bf16(qq[2], qq[3]);
        unsigned p45 = pk_bf16(qq[4], qq[5]), p67 = pk_bf16(qq[6], qq[7]);
        unsigned p89 = pk_bf16(qq[8], qq[9]), pab = pk_bf16(qq[10], qq[11]);
        union { unsigned u[4]; bf16x8 v; } qa;
        qa.u[0] = (quad == 0) ? p01 : (quad == 1) ? p89 : 0u;
        qa.u[1] = (quad == 0) ? p23 : (quad == 1) ? pab : 0u;
        qa.u[2] = (quad == 0) ? p45 : (quad == 1) ? 0x00003F80u : 0u;  // k12 = 1.0
        qa.u[3] = (quad == 0) ? p67 : 0u;
        #pragma unroll
        for (int nt = 0; nt < 5; ++nt) {
            bf16x8 wf = *(const bf16x8*)(wq + (nt * 16 + l15) * 32 + quad * 8);
            f32x4 zz = {0.f, 0.f, 0.f, 0.f};
            zz = __builtin_amdgcn_mfma_f32_16x16x32_bf16(qa.v, wf, zz, 0, 0, 0);
            z0q[nt] = zz[0];
        }
    }

    // ---- one-time LDS inits (wave-private): H tails for BOTH slots ----
    if (quad == 0) {
        bf16x8 one8 = {(short)0x3F80, 0, 0, 0, 0, 0, 0, 0};
        bf16x8 zero8 = {0, 0, 0, 0, 0, 0, 0, 0};
        *(bf16x8*)(HwA + l15 * H_STR + 80) = one8;
        *(bf16x8*)(HwA + l15 * H_STR + 88) = zero8;
        *(bf16x8*)(HwB + l15 * H_STR + 80) = one8;
        *(bf16x8*)(HwB + l15 * H_STR + 88) = zero8;
    }
    {   // A0 row zero-pad (elements 24..31) never changes across chunks
        uint4 z4; z4.x = 0u; z4.y = 0u; z4.z = 0u; z4.w = 0u;
        ((uint4*)(A0w + lane * A0_STR))[3] = z4;
    }

    __syncthreads();   // d0cL/d1cL visible (one-time; not in the hot loop)

    f32x4 acc2 = {0.f, 0.f, 0.f, 0.f};   // phase-2: C[0][e] = sum_t sc_t * k_t[e]

    for (int c = 0; c < 4; ++c) {
        const int t0 = c * 64;
        const int myT = t0 + lane;
        const bool valid = myT < T_LEN;

        // ---- stage A0 row [k bf16(12) | qk bf16(12) | 0-pad(8, static)] ----
        float kk[12];
        if (valid) {
            const float4* kp = (const float4*)(keys + ((size_t)b * T_LEN + myT) * E_DIM);
            float4 k0 = kp[0], k1 = kp[1], k2 = kp[2];
            kk[0]=k0.x; kk[1]=k0.y; kk[2]=k0.z; kk[3]=k0.w;
            kk[4]=k1.x; kk[5]=k1.y; kk[6]=k1.z; kk[7]=k1.w;
            kk[8]=k2.x; kk[9]=k2.y; kk[10]=k2.z; kk[11]=k2.w;
        } else {
            #pragma unroll
            for (int i = 0; i < 12; ++i) kk[i] = 0.0f;
        }
        {
            unsigned kw[6], qkw[6];
            #pragma unroll
            for (int i = 0; i < 6; ++i)
                kw[i] = pk_bf16(kk[2 * i], kk[2 * i + 1]);
            #pragma unroll
            for (int i = 0; i < 6; ++i)
                qkw[i] = pk_bf16(qq[2 * i] * kk[2 * i], qq[2 * i + 1] * kk[2 * i + 1]);
            uint4* dst = (uint4*)(A0w + lane * A0_STR);
            uint4 v0, v1, v2;
            v0.x = kw[0];  v0.y = kw[1];  v0.z = kw[2];  v0.w = kw[3];
            v1.x = kw[4];  v1.y = kw[5];  v1.z = qkw[0]; v1.w = qkw[1];
            v2.x = qkw[2]; v2.y = qkw[3]; v2.z = qkw[4]; v2.w = qkw[5];
            dst[0] = v0; dst[1] = v1; dst[2] = v2;
        }
        // No Asw clear needed — stale scores only multiply zeroed key columns.

        // ---- 2-tile software-pipelined MLP: pairs (0,1),(2,3); c=3: (0,0) masked ----
        const int npairs = (c < 3) ? 2 : 1;
        for (int pp = 0; pp < npairs; ++pp) {
            const int tA = 2 * pp;
            const int tB = (c < 3) ? (2 * pp + 1) : 0;   // c=3: duplicate, B masked
            const bool writeB = (c < 3);

            bf16x8 aA = *(const bf16x8*)(A0w + (tA * 16 + l15) * A0_STR + quad * 8);
            bf16x8 aB = *(const bf16x8*)(A0w + (tB * 16 + l15) * A0_STR + quad * 8);

            // layer 0 + dice0, A/B interleaved (independent chains)
            #pragma unroll
            for (int nt = 0; nt < 5; ++nt) {
                float zq = z0q[nt];
                f32x4 cA = {zq, zq, zq, zq};
                f32x4 cB = {zq, zq, zq, zq};
                cA = __builtin_amdgcn_mfma_f32_16x16x32_bf16(aA, b0f[nt], cA, 0, 0, 0);
                cB = __builtin_amdgcn_mfma_f32_16x16x32_bf16(aB, b0f[nt], cB, 0, 0, 0);
                f32x4 dc = d0cL[nt * 16 + l15];
                float hA[4], hB[4];
                #pragma unroll
                for (int r = 0; r < 4; ++r) {
                    float zA = cA[r], zB = cB[r];
                    float pA = __builtin_amdgcn_rcpf(
                        1.0f + __builtin_amdgcn_exp2f(fmaf(zA, dc.x, dc.y)));
                    float pB = __builtin_amdgcn_rcpf(
                        1.0f + __builtin_amdgcn_exp2f(fmaf(zB, dc.x, dc.y)));
                    hA[r] = zA * fmaf(pA, dc.w, dc.z);
                    hB[r] = zB * fmaf(pB, dc.w, dc.z);
                }
                unsigned a01 = pk_bf16(hA[0], hA[1]), a23 = pk_bf16(hA[2], hA[3]);
                unsigned b01 = pk_bf16(hB[0], hB[1]), b23 = pk_bf16(hB[2], hB[3]);
                ushort_t* hcA = HwA + (quad * 4) * H_STR + nt * 16 + l15;
                ushort_t* hcB = HwB + (quad * 4) * H_STR + nt * 16 + l15;
                hcA[0 * H_STR] = (ushort_t)a01;
                hcA[1 * H_STR] = (ushort_t)(a01 >> 16);
                hcA[2 * H_STR] = (ushort_t)a23;
                hcA[3 * H_STR] = (ushort_t)(a23 >> 16);
                hcB[0 * H_STR] = (ushort_t)b01;
                hcB[1 * H_STR] = (ushort_t)(b01 >> 16);
                hcB[2 * H_STR] = (ushort_t)b23;
                hcB[3 * H_STR] = (ushort_t)(b23 >> 16);
            }

            // layer 1, A/B interleaved
            bf16x8 afA[3], afB[3];
            #pragma unroll
            for (int ks = 0; ks < 3; ++ks) {
                afA[ks] = *(const bf16x8*)(HwA + l15 * H_STR + ks * 32 + quad * 8);
                afB[ks] = *(const bf16x8*)(HwB + l15 * H_STR + ks * 32 + quad * 8);
            }
            float sA[4] = {0.f, 0.f, 0.f, 0.f};
            float sB[4] = {0.f, 0.f, 0.f, 0.f};
            #pragma unroll
            for (int nt = 0; nt < 3; ++nt) {
                f32x4 cA = {0.f, 0.f, 0.f, 0.f};
                f32x4 cB = {0.f, 0.f, 0.f, 0.f};
                #pragma unroll
                for (int ks = 0; ks < 3; ++ks) {
                    cA = __builtin_amdgcn_mfma_f32_16x16x32_bf16(afA[ks], b1f[nt][ks], cA, 0, 0, 0);
                    cB = __builtin_amdgcn_mfma_f32_16x16x32_bf16(afB[ks], b1f[nt][ks], cB, 0, 0, 0);
                }
                f32x4 dc1 = d1cL[nt * 16 + l15];
                #pragma unroll
                for (int r = 0; r < 4; ++r) {
                    float zA = cA[r], zB = cB[r];
                    float pA = __builtin_amdgcn_rcpf(
                        1.0f + __builtin_amdgcn_exp2f(fmaf(zA, dc1.x, dc1.y)));
                    float pB = __builtin_amdgcn_rcpf(
                        1.0f + __builtin_amdgcn_exp2f(fmaf(zB, dc1.x, dc1.y)));
                    sA[r] = fmaf(zA, fmaf(pA, dc1.w, dc1.z), sA[r]);
                    sB[r] = fmaf(zB, fmaf(pB, dc1.w, dc1.z), sB[r]);
                }
            }
            // reduce over 16 j-lanes, A/B interleaved (abias via j=40 channel)
            #pragma unroll
            for (int m = 1; m < 16; m <<= 1) {
                #pragma unroll
                for (int r = 0; r < 4; ++r) {
                    sA[r] += __shfl_xor(sA[r], m, 64);
                    sB[r] += __shfl_xor(sB[r], m, 64);
                }
            }
            if (l15 == 0) {
                {
                    const int tb = t0 + tA * 16 + quad * 4;
                    float v0 = (tb + 0 < T_LEN) ? sA[0] : 0.0f;
                    float v1 = (tb + 1 < T_LEN) ? sA[1] : 0.0f;
                    float v2 = (tb + 2 < T_LEN) ? sA[2] : 0.0f;
                    float v3 = (tb + 3 < T_LEN) ? sA[3] : 0.0f;
                    unsigned lo = pk_bf16(v0, v1), hi = pk_bf16(v2, v3);
                    *(unsigned long long*)(Asw + tA * 16 + quad * 4) =
                        (unsigned long long)lo | ((unsigned long long)hi << 32);
                }
                if (writeB) {
                    const int tb = t0 + tB * 16 + quad * 4;
                    float v0 = (tb + 0 < T_LEN) ? sB[0] : 0.0f;
                    float v1 = (tb + 1 < T_LEN) ? sB[1] : 0.0f;
                    float v2 = (tb + 2 < T_LEN) ? sB[2] : 0.0f;
                    float v3 = (tb + 3 < T_LEN) ? sB[3] : 0.0f;
                    unsigned lo = pk_bf16(v0, v1), hi = pk_bf16(v2, v3);
                    *(unsigned long long*)(Asw + tB * 16 + quad * 4) =
                        (unsigned long long)lo | ((unsigned long long)hi << 32);
                }
            }
        }

        // ---- phase 2 partial: 2 MFMA, K=64 (skip all-zero upper half at c=3) ----
        const int nks = (c < 3) ? 2 : 1;
        for (int ks = 0; ks < nks; ++ks) {
            bf16x8 pa = *(const bf16x8*)(Asw + l15 * 64 + ks * 32 + quad * 8);
            bf16x8 bk;
            #pragma unroll
            for (int j = 0; j < 8; ++j)
                bk[j] = (short)A0w[(ks * 32 + quad * 8 + j) * A0_STR + l15];
            acc2 = __builtin_amdgcn_mfma_f32_16x16x32_bf16(pa, bk, acc2, 0, 0, 0);
        }
    }

    if (quad == 0 && l15 < 12)
        out[(size_t)b * E_DIM + l15] = acc2[0];
}

extern "C" void kernel_launch(void* const* d_in, const int* in_sizes, int n_in,
                              void* d_out, int out_size, void* d_ws, size_t ws_size,
                              hipStream_t stream) {
    const float* query = (const float*)d_in[0];
    const float* keys  = (const float*)d_in[1];
    // d_in[2] = mask (unused: reference bug matmuls unmasked scores)
    const float* W0  = (const float*)d_in[3];
    const float* b0v = (const float*)d_in[4];
    const float* W1  = (const float*)d_in[5];
    const float* b1v = (const float*)d_in[6];
    const float* a0  = (const float*)d_in[7];
    const float* a1  = (const float*)d_in[8];
    const float* mm0 = (const float*)d_in[9];
    const float* mv0 = (const float*)d_in[10];
    const float* mm1 = (const float*)d_in[11];
    const float* mv1 = (const float*)d_in[12];
    const float* ak  = (const float*)d_in[13];
    const float* ab  = (const float*)d_in[14];
    float* out = (float*)d_out;

    hipLaunchKernelGGL(din_prep, dim3(40), dim3(256), 0, stream,
                       W0, b0v, W1, b1v, a0, a1, mm0, mv0, mm1, mv1, ak, ab, d_ws);
    hipLaunchKernelGGL(din_mfma, dim3(B_TOT / 4), dim3(256), 0, stream,
                       query, keys, d_ws, out);
}

// Round 13
// 147.475 us; speedup vs baseline: 1.1154x; 1.0338x over previous
//
#include <hip/hip_runtime.h>
#include <hip/hip_bf16.h>
#include <math.h>

#define B_TOT 4096
#define T_LEN 200
#define E_DIM 12
#define LOG2E 1.44269504088896340736f

typedef __attribute__((ext_vector_type(8))) short bf16x8;
typedef __attribute__((ext_vector_type(4))) float f32x4;
typedef unsigned short ushort_t;

// ---- ws byte layout ----
//  [0     ..  5119]  w0e2 ushort[80][32]: k0..11=Wk_eff, k12..23=Wqk, else 0
//  [5120  .. 10239]  wq   ushort[80][32]: k0..11=Wq_eff, k12=b0, else 0
//  [10240 .. 19455]  w1e  ushort[48][96]: n<40: k<80->W1[k][n], k80->b1[n]; else 0
//  [19456 .. 20735]  d0c  float4[80] = {-rs, mm0*rs, a0, 1-a0},  rs=rsqrt(mv0+eps)*log2e
//  [20736 .. 21503]  d1c  float4[48] = {-rs1, mm1*rs1, a1*ak, (1-a1)*ak}; 0 for j>=40
//
// CONVERGED CONFIG (best benched: 148.9 us total / 55.2 us main, Round 8).
// Session evidence for why this shape:
//  - (256,3) with b0f in regs, b1f streamed from global (L1-hot), d0c/d1c in
//    LDS: natural allocation, WRITE_SIZE ~2 MB (negligible leak).
//  - Forcing lower caps (256,4) spills MFMA frags: +100-180 MB HBM (R5/R7).
//  - Moving b1f/b0f to LDS: neutral (R9/R10). Fused single kernel: -9 us
//    regression, proved ~92 us gap is harness-fixed (R11). H double-buffer
//    + 2-tile pipeline: neutral-negative (R12).
//  - Plateau cause: dice activation floor (~375 sigmoid values/lane/wave,
//    2 trans + 4 VALU each) + cross-pipe stalls; no pipe >60% busy.

__device__ inline unsigned short f2bf(float f) {
    union { float f; unsigned u; } x; x.f = f;
    unsigned r = x.u + 0x7FFFu + ((x.u >> 16) & 1u);
    return (unsigned short)(r >> 16);
}
__device__ inline unsigned pk_bf16(float a, float b) {
    float2 t; t.x = a; t.y = b;
    __hip_bfloat162 h = __float22bfloat162_rn(t);
    union { __hip_bfloat162 h; unsigned u; } cv; cv.h = h;
    return cv.u;
}

__global__ __launch_bounds__(256) void din_prep(
    const float* __restrict__ W0, const float* __restrict__ b0v,
    const float* __restrict__ W1, const float* __restrict__ b1v,
    const float* __restrict__ a0, const float* __restrict__ a1,
    const float* __restrict__ mm0, const float* __restrict__ mv0,
    const float* __restrict__ mm1, const float* __restrict__ mv1,
    const float* __restrict__ ak, void* __restrict__ wsv)
{
    unsigned char* wsb = (unsigned char*)wsv;
    ushort_t* w0e2 = (ushort_t*)wsb;
    ushort_t* wq   = (ushort_t*)(wsb + 5120);
    ushort_t* w1e  = (ushort_t*)(wsb + 10240);
    float* d0c = (float*)(wsb + 19456);
    float* d1c = (float*)(wsb + 20736);

    int idx = blockIdx.x * 256 + threadIdx.x;   // 0..10239
    if (idx < 2560) {
        int n = idx >> 5, k = idx & 31;
        float v = 0.0f;
        if (k < 12)       v = W0[(12 + k) * 80 + n] - W0[(24 + k) * 80 + n];
        else if (k < 24)  v = W0[(36 + (k - 12)) * 80 + n];
        w0e2[n * 32 + k] = f2bf(v);
    } else if (idx < 5120) {
        int v2 = idx - 2560;
        int n = v2 >> 5, k = v2 & 31;
        float v = 0.0f;
        if (k < 12)       v = W0[k * 80 + n] + W0[(24 + k) * 80 + n];
        else if (k == 12) v = b0v[n];
        wq[n * 32 + k] = f2bf(v);
    } else if (idx < 9728) {
        int v2 = idx - 5120;
        int n = v2 / 96, k = v2 - n * 96;
        float v = 0.0f;
        if (n < 40) {
            if (k < 80)       v = W1[k * 40 + n];
            else if (k == 80) v = b1v[n];
        }
        w1e[n * 96 + k] = f2bf(v);
    } else if (idx < 10048) {
        int v2 = idx - 9728;
        int o = v2 >> 2, c = v2 & 3;
        float rs = rsqrtf(mv0[o] + 1e-9f) * LOG2E;
        float val = (c == 0) ? -rs : (c == 1) ? mm0[o] * rs : (c == 2) ? a0[o] : 1.0f - a0[o];
        d0c[o * 4 + c] = val;
    } else {
        int v2 = idx - 10048;
        int j = v2 >> 2, c = v2 & 3;
        float val = 0.0f;
        if (j < 40) {
            float rs = rsqrtf(mv1[j] + 1e-9f) * LOG2E;
            val = (c == 0) ? -rs : (c == 1) ? mm1[j] * rs : (c == 2) ? a1[j] * ak[j]
                                                          : (1.0f - a1[j]) * ak[j];
        }
        d1c[j * 4 + c] = val;
    }
}

#define A0_STR 40   // ushorts/row (32 data + 8 pad) = 80 B: 16B-aligned, banks spread
#define H_STR  104  // ushorts/row (96 data + 8 pad) = 208 B: 16B-aligned, banks spread

// One batch per wave; per-wave-private A0/H/Aseg; one startup barrier only.
__global__ __launch_bounds__(256, 3) void din_mfma(
    const float* __restrict__ query, const float* __restrict__ keys,
    const float* __restrict__ abias_p, const void* __restrict__ wsv,
    float* __restrict__ out)
{
    // Aseg FIRST: phase-2 A-frag garbage rows (l15>0) overflow into A0, in-bounds.
    __shared__ __align__(16) ushort_t Aseg[4 * 64];             //   512 B
    __shared__ __align__(16) ushort_t A0[4 * 64 * A0_STR];      // 20480 B
    __shared__ __align__(16) ushort_t H[4 * 16 * H_STR];        // 13312 B
    __shared__ __align__(16) f32x4 d0cL[80];                    //  1280 B
    __shared__ __align__(16) f32x4 d1cL[48];                    //   768 B
                                                                // 36352 B
    const unsigned char* wsb = (const unsigned char*)wsv;
    const ushort_t* w0e2 = (const ushort_t*)wsb;
    const ushort_t* wq   = (const ushort_t*)(wsb + 5120);
    const ushort_t* w1e  = (const ushort_t*)(wsb + 10240);
    const f32x4* d0cp = (const f32x4*)(wsb + 19456);
    const f32x4* d1cp = (const f32x4*)(wsb + 20736);

    const int tid = threadIdx.x;
    const int lane = tid & 63;
    const int w = tid >> 6;
    const int l15 = lane & 15;
    const int quad = lane >> 4;
    const int b = blockIdx.x * 4 + w;

    ushort_t* A0w = &A0[w * 64 * A0_STR];
    ushort_t* Hw  = &H[w * 16 * H_STR];
    ushort_t* Asw = &Aseg[w * 64];

    // ---- stage dice consts to block-shared LDS ----
    if (tid < 80)        d0cL[tid] = d0cp[tid];
    else if (tid < 128)  d1cL[tid - 80] = d1cp[tid - 80];

    // ---- layer-0 weight fragments, register-resident (20 VGPRs) ----
    bf16x8 b0f[5];
    #pragma unroll
    for (int nt = 0; nt < 5; ++nt)
        b0f[nt] = *(const bf16x8*)(w0e2 + (nt * 16 + l15) * 32 + quad * 8);

    // ---- per-batch query ----
    float qq[12];
    {
        const float4* qp = (const float4*)(query + (size_t)b * E_DIM);
        float4 q0 = qp[0], q1 = qp[1], q2 = qp[2];
        qq[0]=q0.x; qq[1]=q0.y; qq[2]=q0.z; qq[3]=q0.w;
        qq[4]=q1.x; qq[5]=q1.y; qq[6]=q1.z; qq[7]=q1.w;
        qq[8]=q2.x; qq[9]=q2.y; qq[10]=q2.z; qq[11]=q2.w;
    }

    // ---- z0q[5]: per-batch bias row via 5 one-off MFMAs (broadcast A-row) ----
    float z0q[5];
    {
        unsigned p01 = pk_bf16(qq[0], qq[1]), p23 = pk_bf16(qq[2], qq[3]);
        unsigned p45 = pk_bf16(qq[4], qq[5]), p67 = pk_bf16(qq[6], qq[7]);
        unsigned p89 = pk_bf16(qq[8], qq[9]), pab = pk_bf16(qq[10], qq[11]);
        union { unsigned u[4]; bf16x8 v; } qa;
        qa.u[0] = (quad == 0) ? p01 : (quad == 1) ? p89 : 0u;
        qa.u[1] = (quad == 0) ? p23 : (quad == 1) ? pab : 0u;
        qa.u[2] = (quad == 0) ? p45 : (quad == 1) ? 0x00003F80u : 0u;  // k12 = 1.0
        qa.u[3] = (quad == 0) ? p67 : 0u;
        #pragma unroll
        for (int nt = 0; nt < 5; ++nt) {
            bf16x8 wf = *(const bf16x8*)(wq + (nt * 16 + l15) * 32 + quad * 8);
            f32x4 zz = {0.f, 0.f, 0.f, 0.f};
            zz = __builtin_amdgcn_mfma_f32_16x16x32_bf16(qa.v, wf, zz, 0, 0, 0);
            z0q[nt] = zz[0];
        }
    }
    const float abias = abias_p[0];

    // ---- one-time LDS inits ----
    if (quad == 0) {   // H constant tail: k=80 -> 1.0, k=81..95 -> 0
        bf16x8 one8 = {(short)0x3F80, 0, 0, 0, 0, 0, 0, 0};
        bf16x8 zero8 = {0, 0, 0, 0, 0, 0, 0, 0};
        *(bf16x8*)(Hw + l15 * H_STR + 80) = one8;
        *(bf16x8*)(Hw + l15 * H_STR + 88) = zero8;
    }
    {   // A0 row zero-pad (elements 24..31) never changes across chunks
        uint4 z4; z4.x = 0u; z4.y = 0u; z4.z = 0u; z4.w = 0u;
        ((uint4*)(A0w + lane * A0_STR))[3] = z4;
    }

    __syncthreads();   // d0cL/d1cL visible (one-time; not in the hot loop)

    f32x4 acc2 = {0.f, 0.f, 0.f, 0.f};   // phase-2: C[0][e] = sum_t sc_t * k_t[e]

    for (int c = 0; c < 4; ++c) {
        const int t0 = c * 64;
        const int myT = t0 + lane;
        const bool valid = myT < T_LEN;

        // ---- stage A0 row [k bf16(12) | qk bf16(12) | 0-pad(8, static)] ----
        float kk[12];
        if (valid) {
            const float4* kp = (const float4*)(keys + ((size_t)b * T_LEN + myT) * E_DIM);
            float4 k0 = kp[0], k1 = kp[1], k2 = kp[2];
            kk[0]=k0.x; kk[1]=k0.y; kk[2]=k0.z; kk[3]=k0.w;
            kk[4]=k1.x; kk[5]=k1.y; kk[6]=k1.z; kk[7]=k1.w;
            kk[8]=k2.x; kk[9]=k2.y; kk[10]=k2.z; kk[11]=k2.w;
        } else {
            #pragma unroll
            for (int i = 0; i < 12; ++i) kk[i] = 0.0f;
        }
        {
            unsigned kw[6], qkw[6];
            #pragma unroll
            for (int i = 0; i < 6; ++i)
                kw[i] = pk_bf16(kk[2 * i], kk[2 * i + 1]);
            #pragma unroll
            for (int i = 0; i < 6; ++i)
                qkw[i] = pk_bf16(qq[2 * i] * kk[2 * i], qq[2 * i + 1] * kk[2 * i + 1]);
            uint4* dst = (uint4*)(A0w + lane * A0_STR);
            uint4 v0, v1, v2;
            v0.x = kw[0];  v0.y = kw[1];  v0.z = kw[2];  v0.w = kw[3];
            v1.x = kw[4];  v1.y = kw[5];  v1.z = qkw[0]; v1.w = qkw[1];
            v2.x = qkw[2]; v2.y = qkw[3]; v2.z = qkw[4]; v2.w = qkw[5];
            dst[0] = v0; dst[1] = v1; dst[2] = v2;
        }
        // No Asw clear needed — stale scores only multiply zeroed key columns.

        const int ntiles = (c < 3) ? 4 : 1;
        for (int ti = 0; ti < ntiles; ++ti) {
            bf16x8 a0 = *(const bf16x8*)(A0w + (ti * 16 + l15) * A0_STR + quad * 8);

            // layer 0 + dice0, fused per nt (one acc live at a time)
            #pragma unroll
            for (int nt = 0; nt < 5; ++nt) {
                float zq = z0q[nt];
                f32x4 cc = {zq, zq, zq, zq};          // bias folded into C-init
                cc = __builtin_amdgcn_mfma_f32_16x16x32_bf16(a0, b0f[nt], cc, 0, 0, 0);
                f32x4 dc = d0cL[nt * 16 + l15];
                float h[4];
                #pragma unroll
                for (int r = 0; r < 4; ++r) {
                    float z = cc[r];
                    float pg = __builtin_amdgcn_rcpf(
                        1.0f + __builtin_amdgcn_exp2f(fmaf(z, dc.x, dc.y)));
                    h[r] = z * fmaf(pg, dc.w, dc.z);
                }
                unsigned u01 = pk_bf16(h[0], h[1]);
                unsigned u23 = pk_bf16(h[2], h[3]);
                ushort_t* hcol = Hw + (quad * 4) * H_STR + nt * 16 + l15;
                hcol[0 * H_STR] = (ushort_t)u01;
                hcol[1 * H_STR] = (ushort_t)(u01 >> 16);
                hcol[2 * H_STR] = (ushort_t)u23;
                hcol[3 * H_STR] = (ushort_t)(u23 >> 16);
            }

            // layer 1: [16x96]·[96x48], 9 MFMA; B-frags streamed from global (L1-hot)
            bf16x8 af[3];
            #pragma unroll
            for (int ks = 0; ks < 3; ++ks)
                af[ks] = *(const bf16x8*)(Hw + l15 * H_STR + ks * 32 + quad * 8);
            float s[4] = {0.f, 0.f, 0.f, 0.f};
            #pragma unroll
            for (int nt = 0; nt < 3; ++nt) {
                f32x4 cc = {0.f, 0.f, 0.f, 0.f};
                #pragma unroll
                for (int ks = 0; ks < 3; ++ks) {
                    bf16x8 bf = *(const bf16x8*)(w1e + (nt * 16 + l15) * 96 + ks * 32 + quad * 8);
                    cc = __builtin_amdgcn_mfma_f32_16x16x32_bf16(af[ks], bf, cc, 0, 0, 0);
                }
                f32x4 dc1 = d1cL[nt * 16 + l15];
                #pragma unroll
                for (int r = 0; r < 4; ++r) {
                    float z = cc[r];
                    float pg = __builtin_amdgcn_rcpf(
                        1.0f + __builtin_amdgcn_exp2f(fmaf(z, dc1.x, dc1.y)));
                    s[r] = fmaf(z, fmaf(pg, dc1.w, dc1.z), s[r]);
                }
            }
            // reduce over 16 j-lanes
            #pragma unroll
            for (int m = 1; m < 16; m <<= 1) {
                #pragma unroll
                for (int r = 0; r < 4; ++r) s[r] += __shfl_xor(s[r], m, 64);
            }
            if (l15 == 0) {
                const int tb = t0 + ti * 16 + quad * 4;
                float v0 = (tb + 0 < T_LEN) ? s[0] + abias : 0.0f;
                float v1 = (tb + 1 < T_LEN) ? s[1] + abias : 0.0f;
                float v2 = (tb + 2 < T_LEN) ? s[2] + abias : 0.0f;
                float v3 = (tb + 3 < T_LEN) ? s[3] + abias : 0.0f;
                unsigned lo = pk_bf16(v0, v1), hi = pk_bf16(v2, v3);
                unsigned long long pk = (unsigned long long)lo
                                      | ((unsigned long long)hi << 32);
                *(unsigned long long*)(Asw + ti * 16 + quad * 4) = pk;
            }
        }

        // ---- phase 2 partial: 2 MFMA, K=64 (skip all-zero upper half at c=3) ----
        const int nks = (c < 3) ? 2 : 1;
        for (int ks = 0; ks < nks; ++ks) {
            bf16x8 pa = *(const bf16x8*)(Asw + l15 * 64 + ks * 32 + quad * 8);
            bf16x8 bk;
            #pragma unroll
            for (int j = 0; j < 8; ++j)
                bk[j] = (short)A0w[(ks * 32 + quad * 8 + j) * A0_STR + l15];
            acc2 = __builtin_amdgcn_mfma_f32_16x16x32_bf16(pa, bk, acc2, 0, 0, 0);
        }
    }

    if (quad == 0 && l15 < 12)
        out[(size_t)b * E_DIM + l15] = acc2[0];
}

extern "C" void kernel_launch(void* const* d_in, const int* in_sizes, int n_in,
                              void* d_out, int out_size, void* d_ws, size_t ws_size,
                              hipStream_t stream) {
    const float* query = (const float*)d_in[0];
    const float* keys  = (const float*)d_in[1];
    // d_in[2] = mask (unused: reference bug matmuls unmasked scores)
    const float* W0  = (const float*)d_in[3];
    const float* b0v = (const float*)d_in[4];
    const float* W1  = (const float*)d_in[5];
    const float* b1v = (const float*)d_in[6];
    const float* a0  = (const float*)d_in[7];
    const float* a1  = (const float*)d_in[8];
    const float* mm0 = (const float*)d_in[9];
    const float* mv0 = (const float*)d_in[10];
    const float* mm1 = (const float*)d_in[11];
    const float* mv1 = (const float*)d_in[12];
    const float* ak  = (const float*)d_in[13];
    const float* ab  = (const float*)d_in[14];
    float* out = (float*)d_out;

    hipLaunchKernelGGL(din_prep, dim3(40), dim3(256), 0, stream,
                       W0, b0v, W1, b1v, a0, a1, mm0, mv0, mm1, mv1, ak, d_ws);
    hipLaunchKernelGGL(din_mfma, dim3(B_TOT / 4), dim3(256), 0, stream,
                       query, keys, ab, d_ws, out);
}